// Round 6
// baseline (316.673 us; speedup 1.0000x reference)
//
#include <hip/hip_runtime.h>
#include <math.h>

typedef __attribute__((ext_vector_type(8))) short bf16x8;
typedef __attribute__((ext_vector_type(4))) float f32x4;

static __device__ __forceinline__ ushort f2bf(float x) {
    union { float f; unsigned u; } a; a.f = x;
    unsigned r = a.u + 0x7fff + ((a.u >> 16) & 1);   // RNE
    return (ushort)(r >> 16);
}

// ============ fused weight repack (bf16, MFMA A-fragment order) ============
__global__ __launch_bounds__(256) void repack_all_k(const float* __restrict__ c1w,
                                                    const float* __restrict__ c2w,
                                                    const float* __restrict__ c3w,
                                                    const float* __restrict__ fcw,
                                                    ushort* __restrict__ wp1,
                                                    ushort* __restrict__ wp2,
                                                    ushort* __restrict__ wp3,
                                                    ushort* __restrict__ wfc) {
    const int blk = blockIdx.x;
    if (blk < 32) {                       // conv1 w [32][256]
        const int t = blk * 256 + threadIdx.x;
        const int j = t & 7, l = (t >> 3) & 63, kk = (t >> 9) & 7, ot = t >> 12;
        const int oc = ot * 16 + (l & 15);
        const int k  = kk * 32 + ((l >> 4) * 8) + j;
        wp1[t] = f2bf(c1w[oc * 256 + k]);
    } else if (blk < 160) {               // conv2 w [64][512]
        const int t = (blk - 32) * 256 + threadIdx.x;
        const int j = t & 7, l = (t >> 3) & 63, kk = (t >> 9) & 15, wv = t >> 13;
        const int oc = wv * 16 + (l & 15);
        const int k  = kk * 32 + ((l >> 4) * 8) + j;
        wp2[t] = f2bf(c2w[oc * 512 + k]);
    } else if (blk < 304) {               // conv3 w [64][64][9] per kp
        const int t = (blk - 160) * 256 + threadIdx.x;
        const int j = t & 7, l = (t >> 3) & 63, kk = (t >> 9) & 1;
        const int ot = (t >> 10) & 3, kp = t >> 12;
        const int oc = ot * 16 + (l & 15);
        const int ic = kk * 32 + ((l >> 4) * 8) + j;
        wp3[t] = f2bf(c3w[(oc * 64 + ic) * 9 + kp]);
    } else {                              // fc w [3136][256] -> [n][k'=pos*64+oc]
        const int t = (blk - 304) * 256 + threadIdx.x;
        const int n = t / 3136, kp = t % 3136;
        const int pos = kp >> 6, oc = kp & 63;
        wfc[t] = f2bf(fcw[(oc * 49 + pos) * 256 + n]);
    }
}

// ============ mega-fused convs: obs fp32 -> conv1 -> conv2 -> conv3 -> bf16 HWC [1024,49,64]
// 1024 blocks (one image), 512 threads (8 waves). LDS 55.2 KB -> 2 blocks/CU.
__global__ __launch_bounds__(512, 4) void convs_k(const float* __restrict__ curr,
                                                  const float* __restrict__ nxt,
                                                  const ushort* __restrict__ wp1g,
                                                  const float* __restrict__ b1,
                                                  const ushort* __restrict__ wp2g,
                                                  const float* __restrict__ b2,
                                                  const ushort* __restrict__ wp3g,
                                                  const float* __restrict__ b3,
                                                  ushort* __restrict__ a3out) {
    __shared__ ushort stage[4 * 44 * 84];   // 14784 u16 = 29.6 KB; reused as conv2-out (pitch 68)
    __shared__ ushort xt1[12800];           // conv1 out, CHW 32x400 bf16 = 25.6 KB
    const int tid = threadIdx.x;
    const int img = blockIdx.x;             // 0..1023
    const float* xb = (img >= 512 ? nxt + (size_t)(img - 512) * 28224
                                  : curr + (size_t)img * 28224);

    const int w8 = tid >> 6;                // 0..7
    const int l = tid & 63, quad = l >> 4, col = l & 15;
    const bf16x8* wp1f = (const bf16x8*)wp1g;
    const bf16x8* wp2f = (const bf16x8*)wp2g;
    const bf16x8* wp3f = (const bf16x8*)wp3g;

    float bv1[2][4];
    #pragma unroll
    for (int ot = 0; ot < 2; ++ot)
        #pragma unroll
        for (int r = 0; r < 4; ++r) bv1[ot][r] = b1[ot * 16 + quad * 4 + r];

    // ---- conv1: two 44-row supertiles ----
    for (int sup = 0; sup < 2; ++sup) {
        if (sup) __syncthreads();           // readers of stage (conv1 sup0) done
        const int ih0 = sup * 40;
        for (int i = tid; i < 3696; i += 512) {
            const int row = i / 21, c4 = i % 21;
            const int ic = row / 44, rr = row % 44;
            const float4 v = *(const float4*)(xb + ic * 7056 + (ih0 + rr) * 84 + c4 * 4);
            ushort4 u; u.x = f2bf(v.x); u.y = f2bf(v.y); u.z = f2bf(v.z); u.w = f2bf(v.w);
            *(ushort4*)(stage + (ic * 44 + rr) * 84 + c4 * 4) = u;
        }
        __syncthreads();

        for (int t = w8; t < 13; t += 8) {
            const int lraw = t * 16 + col;           // < 208
            const int lpos = lraw < 200 ? lraw : 199;
            const int ohl = lpos / 20, ow = lpos % 20;
            f32x4 acc0 = {0.f, 0.f, 0.f, 0.f}, acc1 = {0.f, 0.f, 0.f, 0.f};
            #pragma unroll
            for (int kk = 0; kk < 8; ++kk) {
                const bf16x8 a0 = wp1f[kk * 64 + l];
                const bf16x8 a1 = wp1f[(8 + kk) * 64 + l];
                const int ickh = kk * 4 + quad;
                const int ic = ickh >> 3, kh = ickh & 7;
                const int base = ic * 3696 + (ohl * 4 + kh) * 84 + ow * 4;
                union { uint2 u2[2]; bf16x8 v; } f;
                f.u2[0] = *(const uint2*)(stage + base);
                f.u2[1] = *(const uint2*)(stage + base + 4);
                acc0 = __builtin_amdgcn_mfma_f32_16x16x32_bf16(a0, f.v, acc0, 0, 0, 0);
                acc1 = __builtin_amdgcn_mfma_f32_16x16x32_bf16(a1, f.v, acc1, 0, 0, 0);
            }
            if (lraw < 200) {
                const int pos = sup * 200 + lraw;
                #pragma unroll
                for (int r = 0; r < 4; ++r) {
                    xt1[(quad * 4 + r) * 400 + pos]      = f2bf(fmaxf(acc0[r] + bv1[0][r], 0.f));
                    xt1[(16 + quad * 4 + r) * 400 + pos] = f2bf(fmaxf(acc1[r] + bv1[1][r], 0.f));
                }
            }
        }
    }
    __syncthreads();      // xt1 complete; stage dead -> alias as conv2 output
    ushort* xt2 = stage;  // 81 x 68 pitch = 5508 u16

    // ---- conv2: wave = (octile, half of pos-tiles) ----
    {
        const int oct = w8 & 3, half = w8 >> 2;
        int ohs[3], ows[3];
        #pragma unroll
        for (int tt = 0; tt < 3; ++tt) {
            int pos = (half * 3 + tt) * 16 + col; if (pos > 80) pos = 80;
            ohs[tt] = pos / 9; ows[tt] = pos % 9;
        }
        const int ic_off = quad >> 1;
        const int kh2    = (quad & 1) * 2;

        float bias_v[4];
        #pragma unroll
        for (int r2 = 0; r2 < 4; ++r2) bias_v[r2] = b2[oct * 16 + quad * 4 + r2];

        f32x4 acc[3];
        #pragma unroll
        for (int tt = 0; tt < 3; ++tt) acc[tt] = (f32x4){0.f, 0.f, 0.f, 0.f};

        for (int kk = 0; kk < 16; ++kk) {
            const bf16x8 a = wp2f[(oct * 16 + kk) * 64 + l];
            const int ic = kk * 2 + ic_off;
            #pragma unroll
            for (int tt = 0; tt < 3; ++tt) {
                const int base = ic * 400 + (ohs[tt] * 2 + kh2) * 20 + ows[tt] * 2;
                const unsigned* p0 = (const unsigned*)(xt1 + base);
                const unsigned* p1 = (const unsigned*)(xt1 + base + 20);
                union { unsigned u[4]; bf16x8 v; } f;
                f.u[0] = p0[0]; f.u[1] = p0[1];
                f.u[2] = p1[0]; f.u[3] = p1[1];
                acc[tt] = __builtin_amdgcn_mfma_f32_16x16x32_bf16(a, f.v, acc[tt], 0, 0, 0);
            }
        }
        __syncthreads();  // all conv1-output reads done before xt2 overwrites stage? (xt2!=xt1; barrier guards stage-read vs write ordering across waves)
        #pragma unroll
        for (int tt = 0; tt < 3; ++tt) {
            const int pos = (half * 3 + tt) * 16 + col;
            if (pos < 81) {
                ushort4 u;
                u.x = f2bf(fmaxf(acc[tt][0] + bias_v[0], 0.f));
                u.y = f2bf(fmaxf(acc[tt][1] + bias_v[1], 0.f));
                u.z = f2bf(fmaxf(acc[tt][2] + bias_v[2], 0.f));
                u.w = f2bf(fmaxf(acc[tt][3] + bias_v[3], 0.f));
                *(ushort4*)(xt2 + pos * 68 + oct * 16 + quad * 4) = u;
            }
        }
    }
    __syncthreads();

    // ---- conv3: wave = (octile, half); 2 pos-tiles each ----
    {
        const int oct = w8 & 3, half = w8 >> 2;
        int ohs[2], ows[2];
        #pragma unroll
        for (int pt = 0; pt < 2; ++pt) {
            int pos = (half * 2 + pt) * 16 + col; if (pos > 48) pos = 48;
            ohs[pt] = pos / 7; ows[pt] = pos % 7;
        }
        float bv[4];
        #pragma unroll
        for (int r = 0; r < 4; ++r) bv[r] = b3[oct * 16 + quad * 4 + r];

        f32x4 acc[2];
        #pragma unroll
        for (int pt = 0; pt < 2; ++pt) acc[pt] = (f32x4){0.f, 0.f, 0.f, 0.f};

        #pragma unroll
        for (int kp = 0; kp < 9; ++kp) {
            const int kh = kp / 3, kw = kp % 3;
            #pragma unroll
            for (int kk = 0; kk < 2; ++kk) {
                const bf16x8 a = wp3f[((kp * 4 + oct) * 2 + kk) * 64 + l];
                #pragma unroll
                for (int pt = 0; pt < 2; ++pt) {
                    const int rpos = (ohs[pt] + kh) * 9 + (ows[pt] + kw);
                    const int base = rpos * 68 + kk * 32 + quad * 8;
                    union { uint2 u2[2]; bf16x8 v; } f;
                    f.u2[0] = *(const uint2*)(xt2 + base);
                    f.u2[1] = *(const uint2*)(xt2 + base + 4);
                    acc[pt] = __builtin_amdgcn_mfma_f32_16x16x32_bf16(a, f.v, acc[pt], 0, 0, 0);
                }
            }
        }
        #pragma unroll
        for (int pt = 0; pt < 2; ++pt) {
            const int pos = (half * 2 + pt) * 16 + col;
            if (pos < 49) {
                ushort4 u;
                u.x = f2bf(fmaxf(acc[pt][0] + bv[0], 0.f));
                u.y = f2bf(fmaxf(acc[pt][1] + bv[1], 0.f));
                u.z = f2bf(fmaxf(acc[pt][2] + bv[2], 0.f));
                u.w = f2bf(fmaxf(acc[pt][3] + bv[3], 0.f));
                *(ushort4*)(a3out + (size_t)img * 3136 + pos * 64 + oct * 16 + quad * 4) = u;
            }
        }
    }
}

// ============ fc MFMA: [1024,3136]bf16 @ wfc[256][3136] -> relu fp32 [1024,256]
__global__ __launch_bounds__(256) void fc_mfma_k(const ushort* __restrict__ a3,
                                                 const ushort* __restrict__ wfc,
                                                 const float* __restrict__ bias,
                                                 float* __restrict__ feat) {
    const int tid = threadIdx.x;
    const int gw = blockIdx.x * 4 + (tid >> 6);    // 0..511
    const int l = tid & 63, q = l >> 4, col = l & 15;
    const int mtile = gw >> 3, np = gw & 7;        // mtile 0..63 covers 1024 rows

    const ushort* arow = a3 + (size_t)(mtile * 16 + col) * 3136;
    const ushort* brow0 = wfc + (size_t)(np * 32 + col) * 3136;
    const ushort* brow1 = brow0 + (size_t)16 * 3136;

    f32x4 acc0 = {0.f, 0.f, 0.f, 0.f}, acc1 = {0.f, 0.f, 0.f, 0.f};
    #pragma unroll 2
    for (int kk = 0; kk < 98; ++kk) {
        const int ko = kk * 32 + q * 8;
        const bf16x8 av = *(const bf16x8*)(arow + ko);
        const bf16x8 b0 = *(const bf16x8*)(brow0 + ko);
        const bf16x8 b1 = *(const bf16x8*)(brow1 + ko);
        acc0 = __builtin_amdgcn_mfma_f32_16x16x32_bf16(av, b0, acc0, 0, 0, 0);
        acc1 = __builtin_amdgcn_mfma_f32_16x16x32_bf16(av, b1, acc1, 0, 0, 0);
    }

    #pragma unroll
    for (int r = 0; r < 4; ++r) {
        const int m = mtile * 16 + q * 4 + r;
        const int n0 = np * 32 + col, n1 = n0 + 16;
        feat[m * 256 + n0] = fmaxf(acc0[r] + bias[n0], 0.f);
        feat[m * 256 + n1] = fmaxf(acc1[r] + bias[n1], 0.f);
    }
}

// ============ fused heads: feat[2][512][256] -> phi_x[512,64], phiYT[64,512], c_y[512]
__global__ __launch_bounds__(256) void heads_k(const float* __restrict__ feat,
                                               const float* __restrict__ e1w,
                                               const float* __restrict__ e1b,
                                               const float* __restrict__ e2w,
                                               const float* __restrict__ e2b,
                                               const float* __restrict__ pw1,
                                               const float* __restrict__ pb1,
                                               const float* __restrict__ pw2,
                                               const float* __restrict__ pb2,
                                               float* __restrict__ phi_x,
                                               float* __restrict__ phiYT,
                                               float* __restrict__ c_y,
                                               float* __restrict__ accbuf) {
    __shared__ float fc[2][256], fn[2][256];
    __shared__ float h1c[2][256], h1n[2][256], hp[2][256];
    const int tid = threadIdx.x;
    const int b0 = blockIdx.x * 2;

    if (blockIdx.x == 0 && tid < 4) accbuf[tid] = 0.f;

    for (int i = tid; i < 512; i += 256) {
        const int rr = i >> 8, c = i & 255;
        fc[rr][c] = feat[(b0 + rr) * 256 + c];
        fn[rr][c] = feat[131072 + (b0 + rr) * 256 + c];
    }
    __syncthreads();

    float ac0 = e1b[tid], ac1 = ac0;
    float an0 = ac0, an1 = ac0;
    float ap0 = pb1[tid], ap1 = ap0;
    for (int k = 0; k < 256; ++k) {
        const float we = e1w[k * 256 + tid];
        const float wpv = pw1[k * 256 + tid];
        ac0 += fc[0][k] * we;  ac1 += fc[1][k] * we;
        an0 += fn[0][k] * we;  an1 += fn[1][k] * we;
        ap0 += fn[0][k] * wpv; ap1 += fn[1][k] * wpv;
    }
    h1c[0][tid] = fmaxf(ac0, 0.f); h1c[1][tid] = fmaxf(ac1, 0.f);
    h1n[0][tid] = fmaxf(an0, 0.f); h1n[1][tid] = fmaxf(an1, 0.f);
    hp[0][tid]  = fmaxf(ap0, 0.f); hp[1][tid]  = fmaxf(ap1, 0.f);
    __syncthreads();

    const int wave = tid >> 6, lane = tid & 63;
    if (wave == 0) {
        #pragma unroll
        for (int rr = 0; rr < 2; ++rr) {
            float s = e2b[lane];
            for (int k = 0; k < 256; ++k) s += h1c[rr][k] * e2w[k * 64 + lane];
            phi_x[(b0 + rr) * 64 + lane] = s;
        }
    } else if (wave == 1) {
        #pragma unroll
        for (int rr = 0; rr < 2; ++rr) {
            float s = e2b[lane];
            for (int k = 0; k < 256; ++k) s += h1n[rr][k] * e2w[k * 64 + lane];
            phiYT[lane * 512 + b0 + rr] = s;
        }
    } else {
        const int rr = wave - 2;
        float s = 0.f;
        #pragma unroll
        for (int q2 = 0; q2 < 4; ++q2) s += hp[rr][lane * 4 + q2] * pw2[lane * 4 + q2];
        #pragma unroll
        for (int off = 32; off > 0; off >>= 1) s += __shfl_down(s, off);
        if (lane == 0) c_y[b0 + rr] = s + pb2[0];
    }
}

// ============ row logits+LSE, fused final loss via atomics
__global__ __launch_bounds__(256) void row_lse_loss_k(const float* __restrict__ phi_x,
                                                      const float* __restrict__ phiYT,
                                                      const float* __restrict__ c_y,
                                                      float* __restrict__ accbuf,
                                                      float* __restrict__ out) {
    const int i = blockIdx.x, tid = threadIdx.x;
    __shared__ float px[64];
    __shared__ float red[256];
    __shared__ float sdiag;
    if (tid < 64) px[tid] = phi_x[i * 64 + tid];
    __syncthreads();

    float lg[2];
    #pragma unroll
    for (int q = 0; q < 2; ++q) {
        const int j = tid + q * 256;
        float m = -1e30f;
        #pragma unroll 8
        for (int k = 0; k < 32; ++k) m = fmaxf(m, px[k] - phiYT[k * 512 + j]);
        const float maxc = fmaxf(m, 0.f);
        float s = 0.f;
        #pragma unroll 8
        for (int k = 32; k < 64; ++k) {
            const float d = px[k] - phiYT[k * 512 + j];
            s += d * d;
        }
        lg[q] = c_y[j] - (maxc + sqrtf(s + 1e-8f));
    }
    if ((i & 255) == tid) sdiag = lg[i >> 8];

    red[tid] = fmaxf(lg[0], lg[1]);
    __syncthreads();
    for (int s = 128; s > 0; s >>= 1) {
        if (tid < s) red[tid] = fmaxf(red[tid], red[tid + s]);
        __syncthreads();
    }
    const float m = red[0];
    __syncthreads();
    red[tid] = expf(lg[0] - m) + expf(lg[1] - m);
    __syncthreads();
    for (int s = 128; s > 0; s >>= 1) {
        if (tid < s) red[tid] += red[tid + s];
        __syncthreads();
    }

    if (tid == 0) {
        const float lse = m + logf(red[0]);
        const float l2 = lse + 1e-6f;
        atomicAdd(&accbuf[0], lse - sdiag);
        atomicAdd(&accbuf[1], l2 * l2);
        __threadfence();
        const unsigned old = atomicAdd((unsigned*)&accbuf[2], 1u);
        if (old == 511u) {
            __threadfence();
            const float s1 = atomicAdd(&accbuf[0], 0.f);
            const float s2 = atomicAdd(&accbuf[1], 0.f);
            out[0] = s1 / 512.f + 0.1f * (s2 / 512.f);
        }
    }
}

extern "C" void kernel_launch(void* const* d_in, const int* in_sizes, int n_in,
                              void* d_out, int out_size, void* d_ws, size_t ws_size,
                              hipStream_t stream) {
    const float* curr = (const float*)d_in[0];
    const float* nxt  = (const float*)d_in[1];
    const float* c1w  = (const float*)d_in[2];
    const float* c1b  = (const float*)d_in[3];
    const float* c2w  = (const float*)d_in[4];
    const float* c2b  = (const float*)d_in[5];
    const float* c3w  = (const float*)d_in[6];
    const float* c3b  = (const float*)d_in[7];
    const float* fcw  = (const float*)d_in[8];
    const float* fcb  = (const float*)d_in[9];
    const float* e1w  = (const float*)d_in[10];
    const float* e1b  = (const float*)d_in[11];
    const float* e2w  = (const float*)d_in[12];
    const float* e2b  = (const float*)d_in[13];
    const float* pw1  = (const float*)d_in[14];
    const float* pb1  = (const float*)d_in[15];
    const float* pw2  = (const float*)d_in[16];
    const float* pb2  = (const float*)d_in[17];

    ushort* a3  = (ushort*)d_ws;                   // 1024 x 3136 = 3,211,264
    ushort* wp1 = a3 + 3211264;                    // 8,192
    ushort* wp2 = wp1 + 8192;                      // 32,768
    ushort* wp3 = wp2 + 32768;                     // 36,864
    ushort* wfc = wp3 + 36864;                     // 802,816
    float*  feat  = (float*)(wfc + 802816);        // 2 x 131,072
    float*  phi_x = feat + 262144;                 // 32,768
    float*  phiYT = phi_x + 32768;                 // 32,768
    float*  c_y   = phiYT + 32768;                 // 512
    float*  acc   = c_y + 512;                     // 4

    repack_all_k<<<3440, 256, 0, stream>>>(c1w, c2w, c3w, fcw, wp1, wp2, wp3, wfc);
    convs_k<<<1024, 512, 0, stream>>>(curr, nxt, wp1, c1b, wp2, c2b, wp3, c3b, a3);
    fc_mfma_k<<<128, 256, 0, stream>>>(a3, wfc, fcb, feat);
    heads_k<<<256, 256, 0, stream>>>(feat, e1w, e1b, e2w, e2b, pw1, pb1, pw2, pb2,
                                     phi_x, phiYT, c_y, acc);
    row_lse_loss_k<<<512, 256, 0, stream>>>(phi_x, phiYT, c_y, acc, (float*)d_out);
}

// Round 7
// 302.103 us; speedup vs baseline: 1.0482x; 1.0482x over previous
//
#include <hip/hip_runtime.h>
#include <math.h>

typedef __attribute__((ext_vector_type(8))) short bf16x8;
typedef __attribute__((ext_vector_type(4))) float f32x4;

static __device__ __forceinline__ ushort f2bf(float x) {
    union { float f; unsigned u; } a; a.f = x;
    unsigned r = a.u + 0x7fff + ((a.u >> 16) & 1);   // RNE
    return (ushort)(r >> 16);
}

#define XT1_P 404   // conv1-out LDS pitch (u16): quad stride 4*404/2=808 dwords = +8 banks -> conflict-free

// ============ fused weight repack (bf16, MFMA A-fragment order) ============
__global__ __launch_bounds__(256) void repack_all_k(const float* __restrict__ c1w,
                                                    const float* __restrict__ c2w,
                                                    const float* __restrict__ c3w,
                                                    const float* __restrict__ fcw,
                                                    ushort* __restrict__ wp1,
                                                    ushort* __restrict__ wp2,
                                                    ushort* __restrict__ wp3,
                                                    ushort* __restrict__ wfc) {
    const int blk = blockIdx.x;
    if (blk < 32) {                       // conv1 w [32][256]
        const int t = blk * 256 + threadIdx.x;
        const int j = t & 7, l = (t >> 3) & 63, kk = (t >> 9) & 7, ot = t >> 12;
        const int oc = ot * 16 + (l & 15);
        const int k  = kk * 32 + ((l >> 4) * 8) + j;
        wp1[t] = f2bf(c1w[oc * 256 + k]);
    } else if (blk < 160) {               // conv2 w [64][512]
        const int t = (blk - 32) * 256 + threadIdx.x;
        const int j = t & 7, l = (t >> 3) & 63, kk = (t >> 9) & 15, wv = t >> 13;
        const int oc = wv * 16 + (l & 15);
        const int k  = kk * 32 + ((l >> 4) * 8) + j;
        wp2[t] = f2bf(c2w[oc * 512 + k]);
    } else if (blk < 304) {               // conv3 w [64][64][9] per kp
        const int t = (blk - 160) * 256 + threadIdx.x;
        const int j = t & 7, l = (t >> 3) & 63, kk = (t >> 9) & 1;
        const int ot = (t >> 10) & 3, kp = t >> 12;
        const int oc = ot * 16 + (l & 15);
        const int ic = kk * 32 + ((l >> 4) * 8) + j;
        wp3[t] = f2bf(c3w[(oc * 64 + ic) * 9 + kp]);
    } else {                              // fc w: COALESCED read fcw[t], scattered bf16 write
        const int t = (blk - 304) * 256 + threadIdx.x;   // 0..802815
        const int k = t >> 8, n = t & 255;               // fcw[k][n], k = oc*49+pos
        const int oc = k / 49, pos = k % 49;
        wfc[n * 3136 + pos * 64 + oc] = f2bf(fcw[t]);
    }
}

// ============ mega-fused convs: obs fp32 -> conv1 -> conv2 -> conv3 -> bf16 HWC [1024,49,64]
// 1024 blocks (one image), 512 threads (8 waves). LDS 40.6 KB -> 4 blocks/CU.
__global__ __launch_bounds__(512, 8) void convs_k(const float* __restrict__ curr,
                                                  const float* __restrict__ nxt,
                                                  const ushort* __restrict__ wp1g,
                                                  const float* __restrict__ b1,
                                                  const ushort* __restrict__ wp2g,
                                                  const float* __restrict__ b2,
                                                  const ushort* __restrict__ wp3g,
                                                  const float* __restrict__ b3,
                                                  ushort* __restrict__ a3out) {
    __shared__ ushort stage[2 * 44 * 84];    // 7392 u16 = 14.8 KB; later aliased as conv2-out (81x68)
    __shared__ ushort xt1[32 * XT1_P];       // conv1 out CHW, 12928 u16 = 25.9 KB
    const int tid = threadIdx.x;
    const int img = blockIdx.x;              // 0..1023
    const float* xb = (img >= 512 ? nxt + (size_t)(img - 512) * 28224
                                  : curr + (size_t)img * 28224);

    const int w8 = tid >> 6;                 // 0..7
    const int l = tid & 63, quad = l >> 4, col = l & 15;
    const bf16x8* wp1f = (const bf16x8*)wp1g;
    const bf16x8* wp2f = (const bf16x8*)wp2g;
    const bf16x8* wp3f = (const bf16x8*)wp3g;

    float bv1[2][4];
    #pragma unroll
    for (int ot = 0; ot < 2; ++ot)
        #pragma unroll
        for (int r = 0; r < 4; ++r) bv1[ot][r] = b1[ot * 16 + quad * 4 + r];

    // ---- conv1: 2 oh-supertiles x 2 channel-halves (k-split staging) ----
    for (int sup = 0; sup < 2; ++sup) {
        f32x4 acc[2][2];                     // [tile][octile]
        #pragma unroll
        for (int ti = 0; ti < 2; ++ti)
            #pragma unroll
            for (int ot = 0; ot < 2; ++ot) acc[ti][ot] = (f32x4){0.f, 0.f, 0.f, 0.f};

        const int ih0 = sup * 40;
        for (int half = 0; half < 2; ++half) {
            if (sup | half) __syncthreads();          // prior readers of stage done
            for (int i = tid; i < 1848; i += 512) {   // 2ch x 44rows x 21 float4
                const int row = i / 21, c4 = i % 21;
                const int icl = row / 44, rr = row % 44;
                const float4 v = *(const float4*)(xb + (half * 2 + icl) * 7056 + (ih0 + rr) * 84 + c4 * 4);
                ushort4 u; u.x = f2bf(v.x); u.y = f2bf(v.y); u.z = f2bf(v.z); u.w = f2bf(v.w);
                *(ushort4*)(stage + (icl * 44 + rr) * 84 + c4 * 4) = u;
            }
            __syncthreads();

            #pragma unroll
            for (int ti = 0; ti < 2; ++ti) {
                const int t = w8 + ti * 8;
                if (t < 13) {
                    const int lraw = t * 16 + col;           // < 208
                    const int lpos = lraw < 200 ? lraw : 199;
                    const int ohl = lpos / 20, ow = lpos % 20;
                    #pragma unroll
                    for (int kk = 0; kk < 4; ++kk) {
                        const int kkg = half * 4 + kk;
                        const bf16x8 a0 = wp1f[kkg * 64 + l];
                        const bf16x8 a1 = wp1f[(8 + kkg) * 64 + l];
                        const int ickh = kkg * 4 + quad;
                        const int icl = (ickh >> 3) & 1, kh = ickh & 7;
                        const int base = icl * 3696 + (ohl * 4 + kh) * 84 + ow * 4;
                        union { uint2 u2[2]; bf16x8 v; } f;
                        f.u2[0] = *(const uint2*)(stage + base);
                        f.u2[1] = *(const uint2*)(stage + base + 4);
                        acc[ti][0] = __builtin_amdgcn_mfma_f32_16x16x32_bf16(a0, f.v, acc[ti][0], 0, 0, 0);
                        acc[ti][1] = __builtin_amdgcn_mfma_f32_16x16x32_bf16(a1, f.v, acc[ti][1], 0, 0, 0);
                    }
                }
            }
        }
        #pragma unroll
        for (int ti = 0; ti < 2; ++ti) {
            const int t = w8 + ti * 8;
            const int lraw = t * 16 + col;
            if (t < 13 && lraw < 200) {
                const int pos = sup * 200 + lraw;
                #pragma unroll
                for (int r = 0; r < 4; ++r) {
                    xt1[(quad * 4 + r) * XT1_P + pos]      = f2bf(fmaxf(acc[ti][0][r] + bv1[0][r], 0.f));
                    xt1[(16 + quad * 4 + r) * XT1_P + pos] = f2bf(fmaxf(acc[ti][1][r] + bv1[1][r], 0.f));
                }
            }
        }
    }
    __syncthreads();      // xt1 complete; stage readers done -> alias stage as conv2 output
    ushort* xt2 = stage;  // 81 x 68 = 5508 u16

    // ---- conv2: wave = (octile, half of pos-tiles) ----
    {
        const int oct = w8 & 3, half = w8 >> 2;
        int ohs[3], ows[3];
        #pragma unroll
        for (int tt = 0; tt < 3; ++tt) {
            int pos = (half * 3 + tt) * 16 + col; if (pos > 80) pos = 80;
            ohs[tt] = pos / 9; ows[tt] = pos % 9;
        }
        const int ic_off = quad >> 1;
        const int kh2    = (quad & 1) * 2;

        float bias_v[4];
        #pragma unroll
        for (int r2 = 0; r2 < 4; ++r2) bias_v[r2] = b2[oct * 16 + quad * 4 + r2];

        f32x4 acc[3];
        #pragma unroll
        for (int tt = 0; tt < 3; ++tt) acc[tt] = (f32x4){0.f, 0.f, 0.f, 0.f};

        for (int kk = 0; kk < 16; ++kk) {
            const bf16x8 a = wp2f[(oct * 16 + kk) * 64 + l];
            const int ic = kk * 2 + ic_off;
            #pragma unroll
            for (int tt = 0; tt < 3; ++tt) {
                const int base = ic * XT1_P + (ohs[tt] * 2 + kh2) * 20 + ows[tt] * 2;
                const unsigned* p0 = (const unsigned*)(xt1 + base);
                const unsigned* p1 = (const unsigned*)(xt1 + base + 20);
                union { unsigned u[4]; bf16x8 v; } f;
                f.u[0] = p0[0]; f.u[1] = p0[1];
                f.u[2] = p1[0]; f.u[3] = p1[1];
                acc[tt] = __builtin_amdgcn_mfma_f32_16x16x32_bf16(a, f.v, acc[tt], 0, 0, 0);
            }
        }
        __syncthreads();  // all xt1/stage reads done before xt2 (stage alias) is written
        #pragma unroll
        for (int tt = 0; tt < 3; ++tt) {
            const int pos = (half * 3 + tt) * 16 + col;
            if (pos < 81) {
                ushort4 u;
                u.x = f2bf(fmaxf(acc[tt][0] + bias_v[0], 0.f));
                u.y = f2bf(fmaxf(acc[tt][1] + bias_v[1], 0.f));
                u.z = f2bf(fmaxf(acc[tt][2] + bias_v[2], 0.f));
                u.w = f2bf(fmaxf(acc[tt][3] + bias_v[3], 0.f));
                *(ushort4*)(xt2 + pos * 68 + oct * 16 + quad * 4) = u;
            }
        }
    }
    __syncthreads();

    // ---- conv3: wave = (octile, half); 2 pos-tiles each ----
    {
        const int oct = w8 & 3, half = w8 >> 2;
        int ohs[2], ows[2];
        #pragma unroll
        for (int pt = 0; pt < 2; ++pt) {
            int pos = (half * 2 + pt) * 16 + col; if (pos > 48) pos = 48;
            ohs[pt] = pos / 7; ows[pt] = pos % 7;
        }
        float bv[4];
        #pragma unroll
        for (int r = 0; r < 4; ++r) bv[r] = b3[oct * 16 + quad * 4 + r];

        f32x4 acc[2];
        #pragma unroll
        for (int pt = 0; pt < 2; ++pt) acc[pt] = (f32x4){0.f, 0.f, 0.f, 0.f};

        #pragma unroll
        for (int kp = 0; kp < 9; ++kp) {
            const int kh = kp / 3, kw = kp % 3;
            #pragma unroll
            for (int kk = 0; kk < 2; ++kk) {
                const bf16x8 a = wp3f[((kp * 4 + oct) * 2 + kk) * 64 + l];
                #pragma unroll
                for (int pt = 0; pt < 2; ++pt) {
                    const int rpos = (ohs[pt] + kh) * 9 + (ows[pt] + kw);
                    const int base = rpos * 68 + kk * 32 + quad * 8;
                    union { uint2 u2[2]; bf16x8 v; } f;
                    f.u2[0] = *(const uint2*)(xt2 + base);
                    f.u2[1] = *(const uint2*)(xt2 + base + 4);
                    acc[pt] = __builtin_amdgcn_mfma_f32_16x16x32_bf16(a, f.v, acc[pt], 0, 0, 0);
                }
            }
        }
        #pragma unroll
        for (int pt = 0; pt < 2; ++pt) {
            const int pos = (half * 2 + pt) * 16 + col;
            if (pos < 49) {
                ushort4 u;
                u.x = f2bf(fmaxf(acc[pt][0] + bv[0], 0.f));
                u.y = f2bf(fmaxf(acc[pt][1] + bv[1], 0.f));
                u.z = f2bf(fmaxf(acc[pt][2] + bv[2], 0.f));
                u.w = f2bf(fmaxf(acc[pt][3] + bv[3], 0.f));
                *(ushort4*)(a3out + (size_t)img * 3136 + pos * 64 + oct * 16 + quad * 4) = u;
            }
        }
    }
}

// ============ fc MFMA: [1024,3136]bf16 @ wfc[256][3136] -> relu fp32 [1024,256]
// grid 512 blocks x 4 waves: 1024 (mtile,ntile) units x 2 K-halves, LDS pair-reduce.
__global__ __launch_bounds__(256) void fc_mfma_k(const ushort* __restrict__ a3,
                                                 const ushort* __restrict__ wfc,
                                                 const float* __restrict__ bias,
                                                 float* __restrict__ feat) {
    __shared__ f32x4 red[2][64];
    const int tid = threadIdx.x;
    const int wid = tid >> 6, l = tid & 63, q = l >> 4, col = l & 15;
    const int unit = blockIdx.x * 2 + (wid >> 1);   // 0..1023
    const int kh = wid & 1;
    const int mtile = unit >> 4, nt = unit & 15;

    const ushort* arow = a3 + (size_t)(mtile * 16 + col) * 3136 + kh * 1568;
    const ushort* brow = wfc + (size_t)(nt * 16 + col) * 3136 + kh * 1568;

    f32x4 acc = {0.f, 0.f, 0.f, 0.f};
    #pragma unroll 7
    for (int kk = 0; kk < 49; ++kk) {
        const int ko = kk * 32 + q * 8;
        const bf16x8 av = *(const bf16x8*)(arow + ko);
        const bf16x8 bv = *(const bf16x8*)(brow + ko);
        acc = __builtin_amdgcn_mfma_f32_16x16x32_bf16(av, bv, acc, 0, 0, 0);
    }

    if (kh == 1) red[wid >> 1][l] = acc;
    __syncthreads();
    if (kh == 0) {
        const f32x4 other = red[wid >> 1][l];
        #pragma unroll
        for (int r = 0; r < 4; ++r) {
            const int m = mtile * 16 + q * 4 + r;
            const int n = nt * 16 + col;
            feat[m * 256 + n] = fmaxf(acc[r] + other[r] + bias[n], 0.f);
        }
    }
}

// ============ fused heads: feat[2][512][256] -> phi_x[512,64], phiYT[64,512], c_y[512]
__global__ __launch_bounds__(256) void heads_k(const float* __restrict__ feat,
                                               const float* __restrict__ e1w,
                                               const float* __restrict__ e1b,
                                               const float* __restrict__ e2w,
                                               const float* __restrict__ e2b,
                                               const float* __restrict__ pw1,
                                               const float* __restrict__ pb1,
                                               const float* __restrict__ pw2,
                                               const float* __restrict__ pb2,
                                               float* __restrict__ phi_x,
                                               float* __restrict__ phiYT,
                                               float* __restrict__ c_y,
                                               float* __restrict__ accbuf) {
    __shared__ float fc[2][256], fn[2][256];
    __shared__ float h1c[2][256], h1n[2][256], hp[2][256];
    const int tid = threadIdx.x;
    const int b0 = blockIdx.x * 2;

    if (blockIdx.x == 0 && tid < 4) accbuf[tid] = 0.f;

    for (int i = tid; i < 512; i += 256) {
        const int rr = i >> 8, c = i & 255;
        fc[rr][c] = feat[(b0 + rr) * 256 + c];
        fn[rr][c] = feat[131072 + (b0 + rr) * 256 + c];
    }
    __syncthreads();

    float ac0 = e1b[tid], ac1 = ac0;
    float an0 = ac0, an1 = ac0;
    float ap0 = pb1[tid], ap1 = ap0;
    for (int k = 0; k < 256; ++k) {
        const float we = e1w[k * 256 + tid];
        const float wpv = pw1[k * 256 + tid];
        ac0 += fc[0][k] * we;  ac1 += fc[1][k] * we;
        an0 += fn[0][k] * we;  an1 += fn[1][k] * we;
        ap0 += fn[0][k] * wpv; ap1 += fn[1][k] * wpv;
    }
    h1c[0][tid] = fmaxf(ac0, 0.f); h1c[1][tid] = fmaxf(ac1, 0.f);
    h1n[0][tid] = fmaxf(an0, 0.f); h1n[1][tid] = fmaxf(an1, 0.f);
    hp[0][tid]  = fmaxf(ap0, 0.f); hp[1][tid]  = fmaxf(ap1, 0.f);
    __syncthreads();

    const int wave = tid >> 6, lane = tid & 63;
    if (wave == 0) {
        #pragma unroll
        for (int rr = 0; rr < 2; ++rr) {
            float s = e2b[lane];
            for (int k = 0; k < 256; ++k) s += h1c[rr][k] * e2w[k * 64 + lane];
            phi_x[(b0 + rr) * 64 + lane] = s;
        }
    } else if (wave == 1) {
        #pragma unroll
        for (int rr = 0; rr < 2; ++rr) {
            float s = e2b[lane];
            for (int k = 0; k < 256; ++k) s += h1n[rr][k] * e2w[k * 64 + lane];
            phiYT[lane * 512 + b0 + rr] = s;
        }
    } else {
        const int rr = wave - 2;
        float s = 0.f;
        #pragma unroll
        for (int q2 = 0; q2 < 4; ++q2) s += hp[rr][lane * 4 + q2] * pw2[lane * 4 + q2];
        #pragma unroll
        for (int off = 32; off > 0; off >>= 1) s += __shfl_down(s, off);
        if (lane == 0) c_y[b0 + rr] = s + pb2[0];
    }
}

// ============ row logits+LSE, fused final loss via atomics
__global__ __launch_bounds__(256) void row_lse_loss_k(const float* __restrict__ phi_x,
                                                      const float* __restrict__ phiYT,
                                                      const float* __restrict__ c_y,
                                                      float* __restrict__ accbuf,
                                                      float* __restrict__ out) {
    const int i = blockIdx.x, tid = threadIdx.x;
    __shared__ float px[64];
    __shared__ float red[256];
    __shared__ float sdiag;
    if (tid < 64) px[tid] = phi_x[i * 64 + tid];
    __syncthreads();

    float lg[2];
    #pragma unroll
    for (int q = 0; q < 2; ++q) {
        const int j = tid + q * 256;
        float m = -1e30f;
        #pragma unroll 8
        for (int k = 0; k < 32; ++k) m = fmaxf(m, px[k] - phiYT[k * 512 + j]);
        const float maxc = fmaxf(m, 0.f);
        float s = 0.f;
        #pragma unroll 8
        for (int k = 32; k < 64; ++k) {
            const float d = px[k] - phiYT[k * 512 + j];
            s += d * d;
        }
        lg[q] = c_y[j] - (maxc + sqrtf(s + 1e-8f));
    }
    if ((i & 255) == tid) sdiag = lg[i >> 8];

    red[tid] = fmaxf(lg[0], lg[1]);
    __syncthreads();
    for (int s = 128; s > 0; s >>= 1) {
        if (tid < s) red[tid] = fmaxf(red[tid], red[tid + s]);
        __syncthreads();
    }
    const float m = red[0];
    __syncthreads();
    red[tid] = expf(lg[0] - m) + expf(lg[1] - m);
    __syncthreads();
    for (int s = 128; s > 0; s >>= 1) {
        if (tid < s) red[tid] += red[tid + s];
        __syncthreads();
    }

    if (tid == 0) {
        const float lse = m + logf(red[0]);
        const float l2 = lse + 1e-6f;
        atomicAdd(&accbuf[0], lse - sdiag);
        atomicAdd(&accbuf[1], l2 * l2);
        __threadfence();
        const unsigned old = atomicAdd((unsigned*)&accbuf[2], 1u);
        if (old == 511u) {
            __threadfence();
            const float s1 = atomicAdd(&accbuf[0], 0.f);
            const float s2 = atomicAdd(&accbuf[1], 0.f);
            out[0] = s1 / 512.f + 0.1f * (s2 / 512.f);
        }
    }
}

extern "C" void kernel_launch(void* const* d_in, const int* in_sizes, int n_in,
                              void* d_out, int out_size, void* d_ws, size_t ws_size,
                              hipStream_t stream) {
    const float* curr = (const float*)d_in[0];
    const float* nxt  = (const float*)d_in[1];
    const float* c1w  = (const float*)d_in[2];
    const float* c1b  = (const float*)d_in[3];
    const float* c2w  = (const float*)d_in[4];
    const float* c2b  = (const float*)d_in[5];
    const float* c3w  = (const float*)d_in[6];
    const float* c3b  = (const float*)d_in[7];
    const float* fcw  = (const float*)d_in[8];
    const float* fcb  = (const float*)d_in[9];
    const float* e1w  = (const float*)d_in[10];
    const float* e1b  = (const float*)d_in[11];
    const float* e2w  = (const float*)d_in[12];
    const float* e2b  = (const float*)d_in[13];
    const float* pw1  = (const float*)d_in[14];
    const float* pb1  = (const float*)d_in[15];
    const float* pw2  = (const float*)d_in[16];
    const float* pb2  = (const float*)d_in[17];

    ushort* a3  = (ushort*)d_ws;                   // 1024 x 3136 = 3,211,264
    ushort* wp1 = a3 + 3211264;                    // 8,192
    ushort* wp2 = wp1 + 8192;                      // 32,768
    ushort* wp3 = wp2 + 32768;                     // 36,864
    ushort* wfc = wp3 + 36864;                     // 802,816
    float*  feat  = (float*)(wfc + 802816);        // 2 x 131,072
    float*  phi_x = feat + 262144;                 // 32,768
    float*  phiYT = phi_x + 32768;                 // 32,768
    float*  c_y   = phiYT + 32768;                 // 512
    float*  acc   = c_y + 512;                     // 4

    repack_all_k<<<3440, 256, 0, stream>>>(c1w, c2w, c3w, fcw, wp1, wp2, wp3, wfc);
    convs_k<<<1024, 512, 0, stream>>>(curr, nxt, wp1, c1b, wp2, c2b, wp3, c3b, a3);
    fc_mfma_k<<<512, 256, 0, stream>>>(a3, wfc, fcb, feat);
    heads_k<<<256, 256, 0, stream>>>(feat, e1w, e1b, e2w, e2b, pw1, pb1, pw2, pb2,
                                     phi_x, phiYT, c_y, acc);
    row_lse_loss_k<<<512, 256, 0, stream>>>(phi_x, phiYT, c_y, acc, (float*)d_out);
}

// Round 8
// 300.605 us; speedup vs baseline: 1.0535x; 1.0050x over previous
//
#include <hip/hip_runtime.h>
#include <math.h>

typedef __attribute__((ext_vector_type(8))) short bf16x8;
typedef __attribute__((ext_vector_type(4))) float f32x4;

static __device__ __forceinline__ ushort f2bf(float x) {
    union { float f; unsigned u; } a; a.f = x;
    unsigned r = a.u + 0x7fff + ((a.u >> 16) & 1);   // RNE
    return (ushort)(r >> 16);
}

// packed fp32x2 -> bf16x2 (RNE). HW instr on gfx950 if builtin available; scalar fallback.
#if defined(__AMDGCN__) && __has_builtin(__builtin_amdgcn_cvt_pk_bf16_f32)
typedef __attribute__((ext_vector_type(2))) __bf16 bf16x2_t;
static __device__ __forceinline__ unsigned f2bf2(float lo, float hi) {
    union { bf16x2_t v; unsigned u; } c;
    c.v = __builtin_amdgcn_cvt_pk_bf16_f32(lo, hi);
    return c.u;
}
#else
static __device__ __forceinline__ unsigned f2bf2(float lo, float hi) {
    return (unsigned)f2bf(lo) | ((unsigned)f2bf(hi) << 16);
}
#endif

#define XT1_P 404   // conv1-out LDS pitch (u16)

// ============ fused weight repack ============
// blocks: [0,32) wp1, [32,160) wp2, [160,304) wp3, [304,500) wfc 64x64 transpose tiles
__global__ __launch_bounds__(256) void repack_all_k(const float* __restrict__ c1w,
                                                    const float* __restrict__ c2w,
                                                    const float* __restrict__ c3w,
                                                    const float* __restrict__ fcw,
                                                    ushort* __restrict__ wp1,
                                                    ushort* __restrict__ wp2,
                                                    ushort* __restrict__ wp3,
                                                    ushort* __restrict__ wfc) {
    const int blk = blockIdx.x;
    if (blk < 32) {                       // conv1 w [32][256]
        const int t = blk * 256 + threadIdx.x;
        const int j = t & 7, l = (t >> 3) & 63, kk = (t >> 9) & 7, ot = t >> 12;
        const int oc = ot * 16 + (l & 15);
        const int k  = kk * 32 + ((l >> 4) * 8) + j;
        wp1[t] = f2bf(c1w[oc * 256 + k]);
    } else if (blk < 160) {               // conv2 w [64][512]
        const int t = (blk - 32) * 256 + threadIdx.x;
        const int j = t & 7, l = (t >> 3) & 63, kk = (t >> 9) & 15, wv = t >> 13;
        const int oc = wv * 16 + (l & 15);
        const int k  = kk * 32 + ((l >> 4) * 8) + j;
        wp2[t] = f2bf(c2w[oc * 512 + k]);
    } else if (blk < 304) {               // conv3 w [64][64][9] per kp
        const int t = (blk - 160) * 256 + threadIdx.x;
        const int j = t & 7, l = (t >> 3) & 63, kk = (t >> 9) & 1;
        const int ot = (t >> 10) & 3, kp = t >> 12;
        const int oc = ot * 16 + (l & 15);
        const int ic = kk * 32 + ((l >> 4) * 8) + j;
        wp3[t] = f2bf(c3w[(oc * 64 + ic) * 9 + kp]);
    } else {
        // fc w [3136][256] -> wfc[n*3136 + pos*64 + oc], tiled 64oc x 64n transpose via LDS.
        __shared__ float tile[64 * 65];
        const int tb = blk - 304;              // 0..195
        const int pos = tb >> 2, n0 = (tb & 3) * 64;
        const int t = threadIdx.x;
        const int w = t >> 6, lane = t & 63;
        #pragma unroll
        for (int r = 0; r < 16; ++r) {         // coalesced 256B row reads
            const int oc = w * 16 + r;
            tile[oc * 65 + lane] = fcw[(oc * 49 + pos) * 256 + n0 + lane];
        }
        __syncthreads();
        #pragma unroll
        for (int r = 0; r < 16; ++r) {         // 128B-contiguous writes per wave
            const int nl = w * 16 + r;
            wfc[(size_t)(n0 + nl) * 3136 + pos * 64 + lane] = f2bf(tile[lane * 65 + nl]);
        }
    }
}

// ============ mega-fused convs: obs fp32 -> conv1 -> conv2 -> conv3 -> bf16 HWC [1024,49,64]
// 1024 blocks (one image), 512 threads (8 waves). LDS 40.6 KB -> 4 blocks/CU.
__global__ __launch_bounds__(512, 8) void convs_k(const float* __restrict__ curr,
                                                  const float* __restrict__ nxt,
                                                  const ushort* __restrict__ wp1g,
                                                  const float* __restrict__ b1,
                                                  const ushort* __restrict__ wp2g,
                                                  const float* __restrict__ b2,
                                                  const ushort* __restrict__ wp3g,
                                                  const float* __restrict__ b3,
                                                  ushort* __restrict__ a3out) {
    __shared__ ushort stage[2 * 44 * 84];    // 7392 u16 = 14.8 KB; later aliased as conv2-out (81x68)
    __shared__ ushort xt1[32 * XT1_P];       // conv1 out CHW, 25.9 KB
    const int tid = threadIdx.x;
    const int img = blockIdx.x;              // 0..1023
    const float* xb = (img >= 512 ? nxt + (size_t)(img - 512) * 28224
                                  : curr + (size_t)img * 28224);

    const int w8 = tid >> 6;                 // 0..7
    const int l = tid & 63, quad = l >> 4, col = l & 15;
    const bf16x8* wp1f = (const bf16x8*)wp1g;
    const bf16x8* wp2f = (const bf16x8*)wp2g;
    const bf16x8* wp3f = (const bf16x8*)wp3g;

    float bv1[2][4];
    #pragma unroll
    for (int ot = 0; ot < 2; ++ot)
        #pragma unroll
        for (int r = 0; r < 4; ++r) bv1[ot][r] = b1[ot * 16 + quad * 4 + r];

    // ---- conv1: 2 oh-supertiles x 2 channel-halves (k-split staging) ----
    for (int sup = 0; sup < 2; ++sup) {
        f32x4 acc[2][2];                     // [tile][octile]
        #pragma unroll
        for (int ti = 0; ti < 2; ++ti)
            #pragma unroll
            for (int ot = 0; ot < 2; ++ot) acc[ti][ot] = (f32x4){0.f, 0.f, 0.f, 0.f};

        const int ih0 = sup * 40;
        for (int half = 0; half < 2; ++half) {
            if (sup | half) __syncthreads();          // prior readers of stage done
            for (int i = tid; i < 1848; i += 512) {   // 2ch x 44rows x 21 float4
                const int row = i / 21, c4 = i % 21;
                const int icl = row / 44, rr = row % 44;
                const float4 v = *(const float4*)(xb + (half * 2 + icl) * 7056 + (ih0 + rr) * 84 + c4 * 4);
                uint2 u; u.x = f2bf2(v.x, v.y); u.y = f2bf2(v.z, v.w);
                *(uint2*)(stage + (icl * 44 + rr) * 84 + c4 * 4) = u;
            }
            __syncthreads();

            #pragma unroll
            for (int ti = 0; ti < 2; ++ti) {
                const int t = w8 + ti * 8;
                if (t < 13) {
                    const int lraw = t * 16 + col;           // < 208
                    const int lpos = lraw < 200 ? lraw : 199;
                    const int ohl = lpos / 20, ow = lpos % 20;
                    #pragma unroll
                    for (int kk = 0; kk < 4; ++kk) {
                        const int kkg = half * 4 + kk;
                        const bf16x8 a0 = wp1f[kkg * 64 + l];
                        const bf16x8 a1 = wp1f[(8 + kkg) * 64 + l];
                        const int ickh = kkg * 4 + quad;
                        const int icl = (ickh >> 3) & 1, kh = ickh & 7;
                        const int base = icl * 3696 + (ohl * 4 + kh) * 84 + ow * 4;
                        union { uint2 u2[2]; bf16x8 v; } f;
                        f.u2[0] = *(const uint2*)(stage + base);
                        f.u2[1] = *(const uint2*)(stage + base + 4);
                        acc[ti][0] = __builtin_amdgcn_mfma_f32_16x16x32_bf16(a0, f.v, acc[ti][0], 0, 0, 0);
                        acc[ti][1] = __builtin_amdgcn_mfma_f32_16x16x32_bf16(a1, f.v, acc[ti][1], 0, 0, 0);
                    }
                }
            }
        }
        #pragma unroll
        for (int ti = 0; ti < 2; ++ti) {
            const int t = w8 + ti * 8;
            const int lraw = t * 16 + col;
            if (t < 13 && lraw < 200) {
                const int pos = sup * 200 + lraw;
                #pragma unroll
                for (int r = 0; r < 4; ++r) {
                    xt1[(quad * 4 + r) * XT1_P + pos]      = f2bf(fmaxf(acc[ti][0][r] + bv1[0][r], 0.f));
                    xt1[(16 + quad * 4 + r) * XT1_P + pos] = f2bf(fmaxf(acc[ti][1][r] + bv1[1][r], 0.f));
                }
            }
        }
    }
    __syncthreads();      // xt1 complete; stage readers done -> alias stage as conv2 output
    ushort* xt2 = stage;  // 81 x 68 = 5508 u16

    // ---- conv2 ----
    {
        const int oct = w8 & 3, half = w8 >> 2;
        int ohs[3], ows[3];
        #pragma unroll
        for (int tt = 0; tt < 3; ++tt) {
            int pos = (half * 3 + tt) * 16 + col; if (pos > 80) pos = 80;
            ohs[tt] = pos / 9; ows[tt] = pos % 9;
        }
        const int ic_off = quad >> 1;
        const int kh2    = (quad & 1) * 2;

        float bias_v[4];
        #pragma unroll
        for (int r2 = 0; r2 < 4; ++r2) bias_v[r2] = b2[oct * 16 + quad * 4 + r2];

        f32x4 acc[3];
        #pragma unroll
        for (int tt = 0; tt < 3; ++tt) acc[tt] = (f32x4){0.f, 0.f, 0.f, 0.f};

        for (int kk = 0; kk < 16; ++kk) {
            const bf16x8 a = wp2f[(oct * 16 + kk) * 64 + l];
            const int ic = kk * 2 + ic_off;
            #pragma unroll
            for (int tt = 0; tt < 3; ++tt) {
                const int base = ic * XT1_P + (ohs[tt] * 2 + kh2) * 20 + ows[tt] * 2;
                const unsigned* p0 = (const unsigned*)(xt1 + base);
                const unsigned* p1 = (const unsigned*)(xt1 + base + 20);
                union { unsigned u[4]; bf16x8 v; } f;
                f.u[0] = p0[0]; f.u[1] = p0[1];
                f.u[2] = p1[0]; f.u[3] = p1[1];
                acc[tt] = __builtin_amdgcn_mfma_f32_16x16x32_bf16(a, f.v, acc[tt], 0, 0, 0);
            }
        }
        __syncthreads();  // all xt1/stage reads done before xt2 (stage alias) is written
        #pragma unroll
        for (int tt = 0; tt < 3; ++tt) {
            const int pos = (half * 3 + tt) * 16 + col;
            if (pos < 81) {
                uint2 u;
                u.x = f2bf2(fmaxf(acc[tt][0] + bias_v[0], 0.f), fmaxf(acc[tt][1] + bias_v[1], 0.f));
                u.y = f2bf2(fmaxf(acc[tt][2] + bias_v[2], 0.f), fmaxf(acc[tt][3] + bias_v[3], 0.f));
                *(uint2*)(xt2 + pos * 68 + oct * 16 + quad * 4) = u;
            }
        }
    }
    __syncthreads();

    // ---- conv3 ----
    {
        const int oct = w8 & 3, half = w8 >> 2;
        int ohs[2], ows[2];
        #pragma unroll
        for (int pt = 0; pt < 2; ++pt) {
            int pos = (half * 2 + pt) * 16 + col; if (pos > 48) pos = 48;
            ohs[pt] = pos / 7; ows[pt] = pos % 7;
        }
        float bv[4];
        #pragma unroll
        for (int r = 0; r < 4; ++r) bv[r] = b3[oct * 16 + quad * 4 + r];

        f32x4 acc[2];
        #pragma unroll
        for (int pt = 0; pt < 2; ++pt) acc[pt] = (f32x4){0.f, 0.f, 0.f, 0.f};

        #pragma unroll
        for (int kp = 0; kp < 9; ++kp) {
            const int kh = kp / 3, kw = kp % 3;
            #pragma unroll
            for (int kk = 0; kk < 2; ++kk) {
                const bf16x8 a = wp3f[((kp * 4 + oct) * 2 + kk) * 64 + l];
                #pragma unroll
                for (int pt = 0; pt < 2; ++pt) {
                    const int rpos = (ohs[pt] + kh) * 9 + (ows[pt] + kw);
                    const int base = rpos * 68 + kk * 32 + quad * 8;
                    union { uint2 u2[2]; bf16x8 v; } f;
                    f.u2[0] = *(const uint2*)(xt2 + base);
                    f.u2[1] = *(const uint2*)(xt2 + base + 4);
                    acc[pt] = __builtin_amdgcn_mfma_f32_16x16x32_bf16(a, f.v, acc[pt], 0, 0, 0);
                }
            }
        }
        #pragma unroll
        for (int pt = 0; pt < 2; ++pt) {
            const int pos = (half * 2 + pt) * 16 + col;
            if (pos < 49) {
                uint2 u;
                u.x = f2bf2(fmaxf(acc[pt][0] + bv[0], 0.f), fmaxf(acc[pt][1] + bv[1], 0.f));
                u.y = f2bf2(fmaxf(acc[pt][2] + bv[2], 0.f), fmaxf(acc[pt][3] + bv[3], 0.f));
                *(uint2*)(a3out + (size_t)img * 3136 + pos * 64 + oct * 16 + quad * 4) = u;
            }
        }
    }
}

// ============ fc MFMA: [1024,3136]bf16 @ wfc[256][3136] -> relu fp32 [1024,256]
__global__ __launch_bounds__(256) void fc_mfma_k(const ushort* __restrict__ a3,
                                                 const ushort* __restrict__ wfc,
                                                 const float* __restrict__ bias,
                                                 float* __restrict__ feat) {
    __shared__ f32x4 red[2][64];
    const int tid = threadIdx.x;
    const int wid = tid >> 6, l = tid & 63, q = l >> 4, col = l & 15;
    const int unit = blockIdx.x * 2 + (wid >> 1);   // 0..1023
    const int kh = wid & 1;
    const int mtile = unit >> 4, nt = unit & 15;

    const ushort* arow = a3 + (size_t)(mtile * 16 + col) * 3136 + kh * 1568;
    const ushort* brow = wfc + (size_t)(nt * 16 + col) * 3136 + kh * 1568;

    f32x4 acc = {0.f, 0.f, 0.f, 0.f};
    #pragma unroll 7
    for (int kk = 0; kk < 49; ++kk) {
        const int ko = kk * 32 + q * 8;
        const bf16x8 av = *(const bf16x8*)(arow + ko);
        const bf16x8 bv = *(const bf16x8*)(brow + ko);
        acc = __builtin_amdgcn_mfma_f32_16x16x32_bf16(av, bv, acc, 0, 0, 0);
    }

    if (kh == 1) red[wid >> 1][l] = acc;
    __syncthreads();
    if (kh == 0) {
        const f32x4 other = red[wid >> 1][l];
        #pragma unroll
        for (int r = 0; r < 4; ++r) {
            const int m = mtile * 16 + q * 4 + r;
            const int n = nt * 16 + col;
            feat[m * 256 + n] = fmaxf(acc[r] + other[r] + bias[n], 0.f);
        }
    }
}

// ============ fused heads ============
__global__ __launch_bounds__(256) void heads_k(const float* __restrict__ feat,
                                               const float* __restrict__ e1w,
                                               const float* __restrict__ e1b,
                                               const float* __restrict__ e2w,
                                               const float* __restrict__ e2b,
                                               const float* __restrict__ pw1,
                                               const float* __restrict__ pb1,
                                               const float* __restrict__ pw2,
                                               const float* __restrict__ pb2,
                                               float* __restrict__ phi_x,
                                               float* __restrict__ phiYT,
                                               float* __restrict__ c_y,
                                               float* __restrict__ accbuf) {
    __shared__ float fc[2][256], fn[2][256];
    __shared__ float h1c[2][256], h1n[2][256], hp[2][256];
    const int tid = threadIdx.x;
    const int b0 = blockIdx.x * 2;

    if (blockIdx.x == 0 && tid < 4) accbuf[tid] = 0.f;

    for (int i = tid; i < 512; i += 256) {
        const int rr = i >> 8, c = i & 255;
        fc[rr][c] = feat[(b0 + rr) * 256 + c];
        fn[rr][c] = feat[131072 + (b0 + rr) * 256 + c];
    }
    __syncthreads();

    float ac0 = e1b[tid], ac1 = ac0;
    float an0 = ac0, an1 = ac0;
    float ap0 = pb1[tid], ap1 = ap0;
    for (int k = 0; k < 256; ++k) {
        const float we = e1w[k * 256 + tid];
        const float wpv = pw1[k * 256 + tid];
        ac0 += fc[0][k] * we;  ac1 += fc[1][k] * we;
        an0 += fn[0][k] * we;  an1 += fn[1][k] * we;
        ap0 += fn[0][k] * wpv; ap1 += fn[1][k] * wpv;
    }
    h1c[0][tid] = fmaxf(ac0, 0.f); h1c[1][tid] = fmaxf(ac1, 0.f);
    h1n[0][tid] = fmaxf(an0, 0.f); h1n[1][tid] = fmaxf(an1, 0.f);
    hp[0][tid]  = fmaxf(ap0, 0.f); hp[1][tid]  = fmaxf(ap1, 0.f);
    __syncthreads();

    const int wave = tid >> 6, lane = tid & 63;
    if (wave == 0) {
        #pragma unroll
        for (int rr = 0; rr < 2; ++rr) {
            float s = e2b[lane];
            for (int k = 0; k < 256; ++k) s += h1c[rr][k] * e2w[k * 64 + lane];
            phi_x[(b0 + rr) * 64 + lane] = s;
        }
    } else if (wave == 1) {
        #pragma unroll
        for (int rr = 0; rr < 2; ++rr) {
            float s = e2b[lane];
            for (int k = 0; k < 256; ++k) s += h1n[rr][k] * e2w[k * 64 + lane];
            phiYT[lane * 512 + b0 + rr] = s;
        }
    } else {
        const int rr = wave - 2;
        float s = 0.f;
        #pragma unroll
        for (int q2 = 0; q2 < 4; ++q2) s += hp[rr][lane * 4 + q2] * pw2[lane * 4 + q2];
        #pragma unroll
        for (int off = 32; off > 0; off >>= 1) s += __shfl_down(s, off);
        if (lane == 0) c_y[b0 + rr] = s + pb2[0];
    }
}

// ============ row logits+LSE, fused final loss via atomics
__global__ __launch_bounds__(256) void row_lse_loss_k(const float* __restrict__ phi_x,
                                                      const float* __restrict__ phiYT,
                                                      const float* __restrict__ c_y,
                                                      float* __restrict__ accbuf,
                                                      float* __restrict__ out) {
    const int i = blockIdx.x, tid = threadIdx.x;
    __shared__ float px[64];
    __shared__ float red[256];
    __shared__ float sdiag;
    if (tid < 64) px[tid] = phi_x[i * 64 + tid];
    __syncthreads();

    float lg[2];
    #pragma unroll
    for (int q = 0; q < 2; ++q) {
        const int j = tid + q * 256;
        float m = -1e30f;
        #pragma unroll 8
        for (int k = 0; k < 32; ++k) m = fmaxf(m, px[k] - phiYT[k * 512 + j]);
        const float maxc = fmaxf(m, 0.f);
        float s = 0.f;
        #pragma unroll 8
        for (int k = 32; k < 64; ++k) {
            const float d = px[k] - phiYT[k * 512 + j];
            s += d * d;
        }
        lg[q] = c_y[j] - (maxc + sqrtf(s + 1e-8f));
    }
    if ((i & 255) == tid) sdiag = lg[i >> 8];

    red[tid] = fmaxf(lg[0], lg[1]);
    __syncthreads();
    for (int s = 128; s > 0; s >>= 1) {
        if (tid < s) red[tid] = fmaxf(red[tid], red[tid + s]);
        __syncthreads();
    }
    const float m = red[0];
    __syncthreads();
    red[tid] = expf(lg[0] - m) + expf(lg[1] - m);
    __syncthreads();
    for (int s = 128; s > 0; s >>= 1) {
        if (tid < s) red[tid] += red[tid + s];
        __syncthreads();
    }

    if (tid == 0) {
        const float lse = m + logf(red[0]);
        const float l2 = lse + 1e-6f;
        atomicAdd(&accbuf[0], lse - sdiag);
        atomicAdd(&accbuf[1], l2 * l2);
        __threadfence();
        const unsigned old = atomicAdd((unsigned*)&accbuf[2], 1u);
        if (old == 511u) {
            __threadfence();
            const float s1 = atomicAdd(&accbuf[0], 0.f);
            const float s2 = atomicAdd(&accbuf[1], 0.f);
            out[0] = s1 / 512.f + 0.1f * (s2 / 512.f);
        }
    }
}

extern "C" void kernel_launch(void* const* d_in, const int* in_sizes, int n_in,
                              void* d_out, int out_size, void* d_ws, size_t ws_size,
                              hipStream_t stream) {
    const float* curr = (const float*)d_in[0];
    const float* nxt  = (const float*)d_in[1];
    const float* c1w  = (const float*)d_in[2];
    const float* c1b  = (const float*)d_in[3];
    const float* c2w  = (const float*)d_in[4];
    const float* c2b  = (const float*)d_in[5];
    const float* c3w  = (const float*)d_in[6];
    const float* c3b  = (const float*)d_in[7];
    const float* fcw  = (const float*)d_in[8];
    const float* fcb  = (const float*)d_in[9];
    const float* e1w  = (const float*)d_in[10];
    const float* e1b  = (const float*)d_in[11];
    const float* e2w  = (const float*)d_in[12];
    const float* e2b  = (const float*)d_in[13];
    const float* pw1  = (const float*)d_in[14];
    const float* pb1  = (const float*)d_in[15];
    const float* pw2  = (const float*)d_in[16];
    const float* pb2  = (const float*)d_in[17];

    ushort* a3  = (ushort*)d_ws;                   // 1024 x 3136 = 3,211,264
    ushort* wp1 = a3 + 3211264;                    // 8,192
    ushort* wp2 = wp1 + 8192;                      // 32,768
    ushort* wp3 = wp2 + 32768;                     // 36,864
    ushort* wfc = wp3 + 36864;                     // 802,816
    float*  feat  = (float*)(wfc + 802816);        // 2 x 131,072
    float*  phi_x = feat + 262144;                 // 32,768
    float*  phiYT = phi_x + 32768;                 // 32,768
    float*  c_y   = phiYT + 32768;                 // 512
    float*  acc   = c_y + 512;                     // 4

    repack_all_k<<<500, 256, 0, stream>>>(c1w, c2w, c3w, fcw, wp1, wp2, wp3, wfc);
    convs_k<<<1024, 512, 0, stream>>>(curr, nxt, wp1, c1b, wp2, c2b, wp3, c3b, a3);
    fc_mfma_k<<<512, 256, 0, stream>>>(a3, wfc, fcb, feat);
    heads_k<<<256, 256, 0, stream>>>(feat, e1w, e1b, e2w, e2b, pw1, pb1, pw2, pb2,
                                     phi_x, phiYT, c_y, acc);
    row_lse_loss_k<<<512, 256, 0, stream>>>(phi_x, phiYT, c_y, acc, (float*)d_out);
}